// Round 5
// baseline (2188.362 us; speedup 1.0000x reference)
//
#include <hip/hip_runtime.h>
#include <hip/hip_bf16.h>
#include <cstdint>
#include <cstddef>

#define B_    8
#define NQ_   1024
#define NK_   1024
#define C_    768
#define H_    12
#define HD_   64
#define HID_  3072
#define M_    (B_*NQ_)          // 8192 rows
#define SCALE_ 0.125f           // 64^-0.5

typedef __hip_bfloat16 bf16;
typedef __attribute__((ext_vector_type(8))) short  s16x8;   // 8 bf16 (4 VGPRs)
typedef __attribute__((ext_vector_type(8))) unsigned short u16x8;
typedef __attribute__((ext_vector_type(4))) float  f32x4;

__device__ __forceinline__ float bf2f(unsigned short u)
{
    union { unsigned int i; float f; } c;
    c.i = ((unsigned int)u) << 16;
    return c.f;
}

// async global->LDS, 16 bytes per lane. LDS dest must be wave-uniform base
// (HW writes base + lane*16); global src is per-lane.
__device__ __forceinline__ void gload_lds16(const void* g, void* l)
{
    __builtin_amdgcn_global_load_lds(
        (const __attribute__((address_space(1))) void*)g,
        (__attribute__((address_space(3))) void*)l, 16, 0, 0);
}

// ---------------------------------------------------------------- f32 -> bf16
__global__ __launch_bounds__(256) void cast_bf16_k(const float* __restrict__ src,
                                                   bf16* __restrict__ dst, int n)
{
    int i = (blockIdx.x * 256 + threadIdx.x) * 4;
    if (i >= n) return;
    float4 v = *(const float4*)(src + i);
    dst[i + 0] = __float2bfloat16(v.x);
    dst[i + 1] = __float2bfloat16(v.y);
    dst[i + 2] = __float2bfloat16(v.z);
    dst[i + 3] = __float2bfloat16(v.w);
}

// ---------------------------------------------------------------- LayerNorm (bf16 out)
__global__ __launch_bounds__(256) void ln_k(const float* __restrict__ in,
                                            const float* __restrict__ g,
                                            const float* __restrict__ bb,
                                            bf16* __restrict__ out)
{
    int row = blockIdx.x;
    int tid = threadIdx.x;
    const float* x = in + (size_t)row * C_;
    float v0 = x[tid], v1 = x[tid + 256], v2 = x[tid + 512];

    __shared__ float red[4];
    float s = v0 + v1 + v2;
    #pragma unroll
    for (int off = 32; off > 0; off >>= 1) s += __shfl_down(s, off, 64);
    if ((tid & 63) == 0) red[tid >> 6] = s;
    __syncthreads();
    float mean = (red[0] + red[1] + red[2] + red[3]) * (1.0f / C_);
    __syncthreads();

    float d0 = v0 - mean, d1 = v1 - mean, d2 = v2 - mean;
    float q = d0 * d0 + d1 * d1 + d2 * d2;
    #pragma unroll
    for (int off = 32; off > 0; off >>= 1) q += __shfl_down(q, off, 64);
    if ((tid & 63) == 0) red[tid >> 6] = q;
    __syncthreads();
    float var = (red[0] + red[1] + red[2] + red[3]) * (1.0f / C_);
    float inv = rsqrtf(var + 1e-5f);

    bf16* o = out + (size_t)row * C_;
    o[tid]       = __float2bfloat16(d0 * inv * g[tid]       + bb[tid]);
    o[tid + 256] = __float2bfloat16(d1 * inv * g[tid + 256] + bb[tid + 256]);
    o[tid + 512] = __float2bfloat16(d2 * inv * g[tid + 512] + bb[tid + 512]);
}

// ---------------------------------------------------------------- MFMA GEMM (NT, bf16 in, f32 acc)
// Out[m,n] = sum_k A[m,k]*W[n,k] (+bias[n]) (gelu?) (+add[m,n])
// 128x128 tile, BK=32, 256 threads = 4 waves in 2x2; wave owns 64x64 (4x4 frags
// of 16x16x32). Linear LDS [128][32] bf16; staged via global_load_lds x16B.
__device__ __forceinline__ float gelu_exact(float x)
{
    return 0.5f * x * (1.0f + erff(x * 0.70710678118654752f));
}

template <int ACT, int OUT_BF16>
__global__ __launch_bounds__(256) void gemm_mfma(const bf16* __restrict__ A,
                                                 const bf16* __restrict__ W,
                                                 const float* __restrict__ bias,
                                                 const float* add,
                                                 void* Out, int N, int K)
{
    __shared__ bf16 As[128 * 32];
    __shared__ bf16 Bs[128 * 32];
    int tid  = threadIdx.x;
    int wave = tid >> 6, lane = tid & 63;
    int wr = wave >> 1, wc = wave & 1;
    int m0 = blockIdx.y * 128, n0 = blockIdx.x * 128;

    // staging: chunk c (of 8 per matrix) = rows [c*16, c*16+16); this wave does
    // chunks {wave, wave+4}. lane l covers row c*16 + (l>>2), elems (l&3)*8..+7.
    // LDS within chunk: lane*16B = row*64B + kpart*16B -> [16][32] row-major.
    int c0 = wave, c1 = wave + 4;
    int sr0 = c0 * 16 + (lane >> 2), sr1 = c1 * 16 + (lane >> 2);
    int sc  = (lane & 3) * 8;
    const bf16* Ab = A + (size_t)m0 * K;
    const bf16* Wb = W + (size_t)n0 * K;

    // fragment read coords (identical for A and B in NT): row l&15, k (l>>4)*8
    int frow = lane & 15;
    int fk   = (lane >> 4) * 8;

    f32x4 acc[4][4];
    #pragma unroll
    for (int i = 0; i < 4; ++i)
        #pragma unroll
        for (int j = 0; j < 4; ++j) {
            acc[i][j][0] = 0.f; acc[i][j][1] = 0.f;
            acc[i][j][2] = 0.f; acc[i][j][3] = 0.f;
        }

    for (int k0 = 0; k0 < K; k0 += 32) {
        __syncthreads();   // all waves done reading previous tile
        gload_lds16(Ab + (size_t)sr0 * K + k0 + sc, As + c0 * 512);
        gload_lds16(Ab + (size_t)sr1 * K + k0 + sc, As + c1 * 512);
        gload_lds16(Wb + (size_t)sr0 * K + k0 + sc, Bs + c0 * 512);
        gload_lds16(Wb + (size_t)sr1 * K + k0 + sc, Bs + c1 * 512);
        __syncthreads();   // compiler drains vmcnt before s_barrier

        s16x8 a[4], b[4];
        #pragma unroll
        for (int mf = 0; mf < 4; ++mf)
            a[mf] = *(const s16x8*)&As[(wr * 64 + mf * 16 + frow) * 32 + fk];
        #pragma unroll
        for (int nf = 0; nf < 4; ++nf)
            b[nf] = *(const s16x8*)&Bs[(wc * 64 + nf * 16 + frow) * 32 + fk];
        #pragma unroll
        for (int mf = 0; mf < 4; ++mf)
            #pragma unroll
            for (int nf = 0; nf < 4; ++nf)
                acc[mf][nf] = __builtin_amdgcn_mfma_f32_16x16x32_bf16(
                    a[mf], b[nf], acc[mf][nf], 0, 0, 0);
    }

    // epilogue: D lane layout col=lane&15, row=(lane>>4)*4+r  [m89-verified]
    int ecol = lane & 15;
    int erow = (lane >> 4) * 4;
    #pragma unroll
    for (int mf = 0; mf < 4; ++mf) {
        #pragma unroll
        for (int nf = 0; nf < 4; ++nf) {
            int col = n0 + wc * 64 + nf * 16 + ecol;
            float bv = bias ? bias[col] : 0.0f;
            #pragma unroll
            for (int r = 0; r < 4; ++r) {
                int row = m0 + wr * 64 + mf * 16 + erow + r;
                size_t o = (size_t)row * N + col;
                float v = acc[mf][nf][r] + bv;
                if (ACT) v = gelu_exact(v);
                if (add) v += add[o];
                if (OUT_BF16) ((bf16*)Out)[o] = __float2bfloat16(v);
                else          ((float*)Out)[o] = v;
            }
        }
    }
}

// ---------------------------------------------------------------- mask layout detect + pack
// Harness may upload the bool mask as 1-byte bools OR int32. Under int32 layout
// every byte at offset%4!=0 in the first 4KB is zero; under byte layout (~50%
// ones) that's impossible (P ~ 2^-3072).
__global__ void detect_mask_k(const unsigned char* __restrict__ m, int* __restrict__ flag)
{
    if (threadIdx.x == 0 && blockIdx.x == 0) {
        int nz = 0;
        for (int i = 0; i < 4096; ++i)
            if ((i & 3) != 0 && m[i] != 0) nz++;
        *flag = (nz == 0) ? 1 : 0;   // 1 = int32 layout, 0 = byte layout
    }
}

// pm[n*16 + w] bit j = mask[n][w*64+j]
__global__ __launch_bounds__(256) void pack_mask_k(const unsigned char* __restrict__ m,
                                                   const int* __restrict__ flag,
                                                   unsigned long long* __restrict__ pm)
{
    int idx = blockIdx.x * 256 + threadIdx.x;    // 16384 words
    unsigned long long v = 0;
    if (*flag) {
        const int* mi = (const int*)m;
        #pragma unroll
        for (int j = 0; j < 64; ++j)
            v |= (unsigned long long)(mi[(size_t)idx * 64 + j] != 0) << j;
    } else {
        const unsigned char* src = m + (size_t)idx * 64;
        #pragma unroll
        for (int j = 0; j < 64; ++j)
            v |= (unsigned long long)(src[j] != 0) << j;
    }
    pm[idx] = v;
}

// ---------------------------------------------------------------- flash attn (bf16 in, fp32 math, bf16 out)
// grid (NQ/256, H, B), 256 threads = 4 waves sharing one K/V 64x64 LDS tile;
// each wave owns 64 q-rows, thread = one q-row. bf16 global tiles are
// converted to f32 once at staging; LDS + inner loop stay f32.
__global__ __launch_bounds__(256) void flash_k(const bf16* __restrict__ Q, int qs,
                                               const bf16* __restrict__ Kp, int ks,
                                               const bf16* __restrict__ Vp, int vs,
                                               bf16* __restrict__ O,
                                               const unsigned long long* __restrict__ pm)
{
    __shared__ float Ks[64][64];
    __shared__ float Vs[64][64];
    int tid = threadIdx.x;
    int h = blockIdx.y, b = blockIdx.z;
    int n = blockIdx.x * 256 + tid;          // wave w covers rows [blk*256+w*64, +64)

    const bf16* qrow = Q + (size_t)(b * NQ_ + n) * qs + h * HD_;
    float q[64];
    #pragma unroll
    for (int i = 0; i < 8; ++i) {
        u16x8 t = *(const u16x8*)(qrow + i * 8);
        #pragma unroll
        for (int j = 0; j < 8; ++j) q[i * 8 + j] = bf2f(t[j]);
    }
    float o[64];
    #pragma unroll
    for (int i = 0; i < 64; ++i) o[i] = 0.0f;
    float m = -1e30f, l = 0.0f;

    const bf16* Kb = Kp + (size_t)(b * NK_) * ks + h * HD_;
    const bf16* Vb = Vp + (size_t)(b * NK_) * vs + h * HD_;

    for (int kt = 0; kt < NK_ / 64; ++kt) {
        __syncthreads();
        // 512 chunks of 8 bf16 per matrix; 256 threads -> 2 iters each
        #pragma unroll
        for (int f = tid; f < 512; f += 256) {
            int r = f >> 3, c = (f & 7) * 8;
            u16x8 kv = *(const u16x8*)(Kb + (size_t)(kt * 64 + r) * ks + c);
            u16x8 vv = *(const u16x8*)(Vb + (size_t)(kt * 64 + r) * vs + c);
            float4 ka = {bf2f(kv[0]), bf2f(kv[1]), bf2f(kv[2]), bf2f(kv[3])};
            float4 kb2 = {bf2f(kv[4]), bf2f(kv[5]), bf2f(kv[6]), bf2f(kv[7])};
            float4 va = {bf2f(vv[0]), bf2f(vv[1]), bf2f(vv[2]), bf2f(vv[3])};
            float4 vb2 = {bf2f(vv[4]), bf2f(vv[5]), bf2f(vv[6]), bf2f(vv[7])};
            *(float4*)&Ks[r][c]     = ka;
            *(float4*)&Ks[r][c + 4] = kb2;
            *(float4*)&Vs[r][c]     = va;
            *(float4*)&Vs[r][c + 4] = vb2;
        }
        __syncthreads();
        unsigned long long mb = pm ? pm[(size_t)n * 16 + kt] : ~0ull;

        for (int j = 0; j < 64; ++j) {
            float s0 = 0.f, s1 = 0.f, s2 = 0.f, s3 = 0.f;   // 4 partial chains
            #pragma unroll
            for (int dv = 0; dv < 16; ++dv) {
                float4 kv = *(const float4*)&Ks[j][dv * 4];   // uniform addr: broadcast
                s0 = fmaf(q[dv*4+0], kv.x, s0);
                s1 = fmaf(q[dv*4+1], kv.y, s1);
                s2 = fmaf(q[dv*4+2], kv.z, s2);
                s3 = fmaf(q[dv*4+3], kv.w, s3);
            }
            float sc = ((s0 + s1) + (s2 + s3)) * SCALE_;
            bool ok = ((mb >> j) & 1ull) != 0;
            if (!ok) sc = -1e30f;
            float mn = fmaxf(m, sc);
            float corr = __expf(m - mn);             // m=-1e30 start -> corr=0 on first real key
            float p = ok ? __expf(sc - mn) : 0.0f;   // masked keys contribute exactly 0
            l = l * corr + p;
            m = mn;
            #pragma unroll
            for (int dv = 0; dv < 16; ++dv) {
                float4 vv = *(const float4*)&Vs[j][dv * 4];   // broadcast
                o[dv*4+0] = o[dv*4+0] * corr + p * vv.x;
                o[dv*4+1] = o[dv*4+1] * corr + p * vv.y;
                o[dv*4+2] = o[dv*4+2] * corr + p * vv.z;
                o[dv*4+3] = o[dv*4+3] * corr + p * vv.w;
            }
        }
    }

    float invl = 1.0f / l;
    bf16* orow = O + (size_t)(b * NQ_ + n) * C_ + h * HD_;
    #pragma unroll
    for (int i = 0; i < 16; ++i) {
        union { ushort4 u; bf16 h[4]; } pk;
        pk.h[0] = __float2bfloat16(o[4*i+0] * invl);
        pk.h[1] = __float2bfloat16(o[4*i+1] * invl);
        pk.h[2] = __float2bfloat16(o[4*i+2] * invl);
        pk.h[3] = __float2bfloat16(o[4*i+3] * invl);
        *(ushort4*)(orow + i * 4) = pk.u;
    }
}

// ---------------------------------------------------------------- launch
extern "C" void kernel_launch(void* const* d_in, const int* in_sizes, int n_in,
                              void* d_out, int out_size, void* d_ws, size_t ws_size,
                              hipStream_t stream)
{
    const float* x           = (const float*)d_in[0];
    const float* y           = (const float*)d_in[1];
    const unsigned char* mask = (const unsigned char*)d_in[4];
    const float* qkv_w       = (const float*)d_in[5];
    const float* attn_proj_w = (const float*)d_in[6];
    const float* attn_proj_b = (const float*)d_in[7];
    const float* q_w         = (const float*)d_in[8];
    const float* k_w         = (const float*)d_in[9];
    const float* v_w         = (const float*)d_in[10];
    const float* ca_proj_w   = (const float*)d_in[11];
    const float* ca_proj_b   = (const float*)d_in[12];
    const float* fc1_w       = (const float*)d_in[13];
    const float* fc1_b       = (const float*)d_in[14];
    const float* fc2_w       = (const float*)d_in[15];
    const float* fc2_b       = (const float*)d_in[16];
    const float* ln1_g = (const float*)d_in[17], *ln1_b = (const float*)d_in[18];
    const float* ln2_g = (const float*)d_in[19], *ln2_b = (const float*)d_in[20];
    const float* ln3_g = (const float*)d_in[21], *ln3_b = (const float*)d_in[22];
    const float* lny_g = (const float*)d_in[23], *lny_b = (const float*)d_in[24];

    float* xo = (float*)d_out;
    float* ws = (float*)d_ws;
    // workspace layout (float-unit offsets):
    bf16*  qkvBuf = (bf16*)ws;                        // bf16 8192x2304 = 9,437,184 f-equiv (self qkv / cross q,k,v)
    bf16*  hBuf   = (bf16*)ws;                        // bf16 8192x3072 = 12,582,912 f-equiv (fc1 out; disjoint lifetime)
    bf16*  lnBuf  = (bf16*)(ws + 18874368);           // bf16 8192x768  -> 3,145,728 f
    bf16*  oBuf   = (bf16*)(ws + 22020096);           // bf16 8192x768
    bf16*  yBuf   = (bf16*)(ws + 25165824);           // bf16 8192x768
    bf16*  wts    = (bf16*)(ws + 28311552);           // 9,437,184 bf16 = 4,718,592 f
    unsigned long long* pm = (unsigned long long*)(ws + 33030144);  // 16384 u64
    int* mflag = (int*)(ws + 33030144 + 32768);

    bf16* qkv_w16  = wts;
    bf16* attn_w16 = wts + 1769472;
    bf16* q_w16    = wts + 2359296;
    bf16* k_w16    = wts + 2949120;
    bf16* v_w16    = wts + 3538944;
    bf16* ca_w16   = wts + 4128768;
    bf16* fc1_w16  = wts + 4718592;
    bf16* fc2_w16  = wts + 7077888;

    bf16* q_c = qkvBuf;                 // cross q (bf16, 8192x768 each)
    bf16* k_c = qkvBuf + 6291456;
    bf16* v_c = qkvBuf + 12582912;

    // weight casts (independent; ~57 MB total traffic)
    cast_bf16_k<<<1769472/1024, 256, 0, stream>>>(qkv_w,       qkv_w16, 1769472);
    cast_bf16_k<<< 589824/1024, 256, 0, stream>>>(attn_proj_w, attn_w16, 589824);
    cast_bf16_k<<< 589824/1024, 256, 0, stream>>>(q_w,         q_w16,   589824);
    cast_bf16_k<<< 589824/1024, 256, 0, stream>>>(k_w,         k_w16,   589824);
    cast_bf16_k<<< 589824/1024, 256, 0, stream>>>(v_w,         v_w16,   589824);
    cast_bf16_k<<< 589824/1024, 256, 0, stream>>>(ca_proj_w,   ca_w16,  589824);
    cast_bf16_k<<<2359296/1024, 256, 0, stream>>>(fc1_w,       fc1_w16, 2359296);
    cast_bf16_k<<<2359296/1024, 256, 0, stream>>>(fc2_w,       fc2_w16, 2359296);

    // mask
    detect_mask_k<<<1, 64, 0, stream>>>(mask, mflag);
    pack_mask_k<<<64, 256, 0, stream>>>(mask, mflag, pm);

    // 1. h1 = ln1(x) -> bf16
    ln_k<<<M_, 256, 0, stream>>>(x, ln1_g, ln1_b, lnBuf);
    // 2. qkv = h1 @ qkv_w^T -> bf16
    gemm_mfma<0,1><<<dim3(2304/128, M_/128), 256, 0, stream>>>(lnBuf, qkv_w16, nullptr, nullptr, qkvBuf, 2304, 768);
    // 3. self flash attention -> oBuf bf16
    flash_k<<<dim3(NQ_/256, H_, B_), 256, 0, stream>>>(qkvBuf, 2304, qkvBuf + 768, 2304, qkvBuf + 1536, 2304, oBuf, nullptr);
    // 4. x1 = x + o @ attn_proj_w^T + b -> xo f32
    gemm_mfma<0,0><<<dim3(768/128, M_/128), 256, 0, stream>>>(oBuf, attn_w16, attn_proj_b, x, xo, 768, 768);
    // 5. y_ = lny(y) -> bf16
    ln_k<<<M_, 256, 0, stream>>>(y, lny_g, lny_b, yBuf);
    // 6. h2 = ln2(x1) -> bf16
    ln_k<<<M_, 256, 0, stream>>>(xo, ln2_g, ln2_b, lnBuf);
    // 7-9. cross q,k,v -> bf16
    gemm_mfma<0,1><<<dim3(768/128, M_/128), 256, 0, stream>>>(lnBuf, q_w16, nullptr, nullptr, q_c, 768, 768);
    gemm_mfma<0,1><<<dim3(768/128, M_/128), 256, 0, stream>>>(yBuf,  k_w16, nullptr, nullptr, k_c, 768, 768);
    gemm_mfma<0,1><<<dim3(768/128, M_/128), 256, 0, stream>>>(yBuf,  v_w16, nullptr, nullptr, v_c, 768, 768);
    // 10. cross flash attention (masked) -> oBuf bf16
    flash_k<<<dim3(NQ_/256, H_, B_), 256, 0, stream>>>(q_c, 768, k_c, 768, v_c, 768, oBuf, pm);
    // 11. x2 = x1 + o @ ca_proj_w^T + b (in-place on xo)
    gemm_mfma<0,0><<<dim3(768/128, M_/128), 256, 0, stream>>>(oBuf, ca_w16, ca_proj_b, xo, xo, 768, 768);
    // 12. h3 = ln3(x2) -> bf16
    ln_k<<<M_, 256, 0, stream>>>(xo, ln3_g, ln3_b, lnBuf);
    // 13. h = gelu(h3 @ fc1_w^T + b) -> hBuf bf16
    gemm_mfma<1,1><<<dim3(3072/128, M_/128), 256, 0, stream>>>(lnBuf, fc1_w16, fc1_b, nullptr, hBuf, 3072, 768);
    // 14. x3 = x2 + h @ fc2_w^T + b (in-place on xo)
    gemm_mfma<0,0><<<dim3(768/128, M_/128), 256, 0, stream>>>(hBuf, fc2_w16, fc2_b, xo, xo, 768, 3072);
    // 15. y passthrough
    hipMemcpyAsync(xo + 6291456, y, (size_t)6291456 * 4, hipMemcpyDeviceToDevice, stream);
}

// Round 6
// 917.648 us; speedup vs baseline: 2.3847x; 2.3847x over previous
//
#include <hip/hip_runtime.h>
#include <hip/hip_bf16.h>
#include <cstdint>
#include <cstddef>

#define B_    8
#define NQ_   1024
#define NK_   1024
#define C_    768
#define H_    12
#define HD_   64
#define HID_  3072
#define M_    (B_*NQ_)          // 8192 rows
#define SCALE_ 0.125f           // 64^-0.5

typedef __hip_bfloat16 bf16;
typedef __attribute__((ext_vector_type(8))) short  s16x8;   // 8 bf16 (4 VGPRs)
typedef __attribute__((ext_vector_type(8))) unsigned short u16x8;
typedef __attribute__((ext_vector_type(4))) float  f32x4;

__device__ __forceinline__ float bf2f(unsigned short u)
{
    union { unsigned int i; float f; } c;
    c.i = ((unsigned int)u) << 16;
    return c.f;
}

// async global->LDS, 16 bytes per lane. LDS dest must be wave-uniform base
// (HW writes base + lane*16); global src is per-lane.
__device__ __forceinline__ void gload_lds16(const void* g, void* l)
{
    __builtin_amdgcn_global_load_lds(
        (const __attribute__((address_space(1))) void*)g,
        (__attribute__((address_space(3))) void*)l, 16, 0, 0);
}

// ---------------------------------------------------------------- f32 -> bf16
__global__ __launch_bounds__(256) void cast_bf16_k(const float* __restrict__ src,
                                                   bf16* __restrict__ dst, int n)
{
    int i = (blockIdx.x * 256 + threadIdx.x) * 4;
    if (i >= n) return;
    float4 v = *(const float4*)(src + i);
    dst[i + 0] = __float2bfloat16(v.x);
    dst[i + 1] = __float2bfloat16(v.y);
    dst[i + 2] = __float2bfloat16(v.z);
    dst[i + 3] = __float2bfloat16(v.w);
}

// ---------------------------------------------------------------- LayerNorm (bf16 out)
__global__ __launch_bounds__(256) void ln_k(const float* __restrict__ in,
                                            const float* __restrict__ g,
                                            const float* __restrict__ bb,
                                            bf16* __restrict__ out)
{
    int row = blockIdx.x;
    int tid = threadIdx.x;
    const float* x = in + (size_t)row * C_;
    float v0 = x[tid], v1 = x[tid + 256], v2 = x[tid + 512];

    __shared__ float red[4];
    float s = v0 + v1 + v2;
    #pragma unroll
    for (int off = 32; off > 0; off >>= 1) s += __shfl_down(s, off, 64);
    if ((tid & 63) == 0) red[tid >> 6] = s;
    __syncthreads();
    float mean = (red[0] + red[1] + red[2] + red[3]) * (1.0f / C_);
    __syncthreads();

    float d0 = v0 - mean, d1 = v1 - mean, d2 = v2 - mean;
    float q = d0 * d0 + d1 * d1 + d2 * d2;
    #pragma unroll
    for (int off = 32; off > 0; off >>= 1) q += __shfl_down(q, off, 64);
    if ((tid & 63) == 0) red[tid >> 6] = q;
    __syncthreads();
    float var = (red[0] + red[1] + red[2] + red[3]) * (1.0f / C_);
    float inv = rsqrtf(var + 1e-5f);

    bf16* o = out + (size_t)row * C_;
    o[tid]       = __float2bfloat16(d0 * inv * g[tid]       + bb[tid]);
    o[tid + 256] = __float2bfloat16(d1 * inv * g[tid + 256] + bb[tid + 256]);
    o[tid + 512] = __float2bfloat16(d2 * inv * g[tid + 512] + bb[tid + 512]);
}

// ---------------------------------------------------------------- MFMA GEMM (NT, bf16 in, f32 acc)
__device__ __forceinline__ float gelu_exact(float x)
{
    return 0.5f * x * (1.0f + erff(x * 0.70710678118654752f));
}

template <int ACT, int OUT_BF16>
__global__ __launch_bounds__(256) void gemm_mfma(const bf16* __restrict__ A,
                                                 const bf16* __restrict__ W,
                                                 const float* __restrict__ bias,
                                                 const float* add,
                                                 void* Out, int N, int K)
{
    __shared__ bf16 As[128 * 32];
    __shared__ bf16 Bs[128 * 32];
    int tid  = threadIdx.x;
    int wave = tid >> 6, lane = tid & 63;
    int wr = wave >> 1, wc = wave & 1;
    int m0 = blockIdx.y * 128, n0 = blockIdx.x * 128;

    int c0 = wave, c1 = wave + 4;
    int sr0 = c0 * 16 + (lane >> 2), sr1 = c1 * 16 + (lane >> 2);
    int sc  = (lane & 3) * 8;
    const bf16* Ab = A + (size_t)m0 * K;
    const bf16* Wb = W + (size_t)n0 * K;

    int frow = lane & 15;
    int fk   = (lane >> 4) * 8;

    f32x4 acc[4][4];
    #pragma unroll
    for (int i = 0; i < 4; ++i)
        #pragma unroll
        for (int j = 0; j < 4; ++j) {
            acc[i][j][0] = 0.f; acc[i][j][1] = 0.f;
            acc[i][j][2] = 0.f; acc[i][j][3] = 0.f;
        }

    for (int k0 = 0; k0 < K; k0 += 32) {
        __syncthreads();
        gload_lds16(Ab + (size_t)sr0 * K + k0 + sc, As + c0 * 512);
        gload_lds16(Ab + (size_t)sr1 * K + k0 + sc, As + c1 * 512);
        gload_lds16(Wb + (size_t)sr0 * K + k0 + sc, Bs + c0 * 512);
        gload_lds16(Wb + (size_t)sr1 * K + k0 + sc, Bs + c1 * 512);
        __syncthreads();

        s16x8 a[4], b[4];
        #pragma unroll
        for (int mf = 0; mf < 4; ++mf)
            a[mf] = *(const s16x8*)&As[(wr * 64 + mf * 16 + frow) * 32 + fk];
        #pragma unroll
        for (int nf = 0; nf < 4; ++nf)
            b[nf] = *(const s16x8*)&Bs[(wc * 64 + nf * 16 + frow) * 32 + fk];
        #pragma unroll
        for (int mf = 0; mf < 4; ++mf)
            #pragma unroll
            for (int nf = 0; nf < 4; ++nf)
                acc[mf][nf] = __builtin_amdgcn_mfma_f32_16x16x32_bf16(
                    a[mf], b[nf], acc[mf][nf], 0, 0, 0);
    }

    int ecol = lane & 15;
    int erow = (lane >> 4) * 4;
    #pragma unroll
    for (int mf = 0; mf < 4; ++mf) {
        #pragma unroll
        for (int nf = 0; nf < 4; ++nf) {
            int col = n0 + wc * 64 + nf * 16 + ecol;
            float bv = bias ? bias[col] : 0.0f;
            #pragma unroll
            for (int r = 0; r < 4; ++r) {
                int row = m0 + wr * 64 + mf * 16 + erow + r;
                size_t o = (size_t)row * N + col;
                float v = acc[mf][nf][r] + bv;
                if (ACT) v = gelu_exact(v);
                if (add) v += add[o];
                if (OUT_BF16) ((bf16*)Out)[o] = __float2bfloat16(v);
                else          ((float*)Out)[o] = v;
            }
        }
    }
}

// ---------------------------------------------------------------- mask layout detect + pack
__global__ void detect_mask_k(const unsigned char* __restrict__ m, int* __restrict__ flag)
{
    if (threadIdx.x == 0 && blockIdx.x == 0) {
        int nz = 0;
        for (int i = 0; i < 4096; ++i)
            if ((i & 3) != 0 && m[i] != 0) nz++;
        *flag = (nz == 0) ? 1 : 0;   // 1 = int32 layout, 0 = byte layout
    }
}

// pm[n*16 + w] bit j = mask[n][w*64+j]
__global__ __launch_bounds__(256) void pack_mask_k(const unsigned char* __restrict__ m,
                                                   const int* __restrict__ flag,
                                                   unsigned long long* __restrict__ pm)
{
    int idx = blockIdx.x * 256 + threadIdx.x;    // 16384 words
    unsigned long long v = 0;
    if (*flag) {
        const int* mi = (const int*)m;
        #pragma unroll
        for (int j = 0; j < 64; ++j)
            v |= (unsigned long long)(mi[(size_t)idx * 64 + j] != 0) << j;
    } else {
        const unsigned char* src = m + (size_t)idx * 64;
        #pragma unroll
        for (int j = 0; j < 64; ++j)
            v |= (unsigned long long)(src[j] != 0) << j;
    }
    pm[idx] = v;
}

// ---------------------------------------------------------------- MFMA flash attention
// grid (NQ/64, H, B), 256 thr = 4 waves; wave owns 16 q-rows. KV tile = 64 keys.
// QK^T and PV on MFMA 16x16x32 (layouts identical to the validated GEMM).
// All LDS tiles swizzled: 16B-unit ^= (row&7)  (row stride 128B -> conflict-free b128).
// K staged via global_load_lds with PRE-SWIZZLED global source (LDS dest linear).
__device__ __forceinline__ int sw_u(int row, int u)      // element offset of 8-elem unit
{
    return (row << 6) + ((u ^ (row & 7)) << 3);
}

__global__ __launch_bounds__(256) void flash_mfma_k(const bf16* __restrict__ Q, int qs,
                                                    const bf16* __restrict__ Kp, int ks,
                                                    const bf16* __restrict__ Vp, int vs,
                                                    bf16* __restrict__ O,
                                                    const unsigned long long* __restrict__ pm)
{
    __shared__ unsigned short Ks[64 * 64];        // K[key][d]   (swizzled)
    __shared__ unsigned short Vt[64 * 64];        // V^T[d][key] (swizzled)
    __shared__ unsigned short Pl[4][16 * 64];     // per-wave P[q][key] (swizzled)

    int tid = threadIdx.x;
    int w   = tid >> 6, l = tid & 63;
    int h = blockIdx.y, b = blockIdx.z;
    int qn0 = blockIdx.x * 64 + w * 16;           // wave's first q row (seq index)

    // Q a-frags: lane holds row l&15, d-offsets (l>>4)*8 (+32 for second MFMA)
    const bf16* qp = Q + (size_t)(b * NQ_ + qn0 + (l & 15)) * qs + h * HD_ + (l >> 4) * 8;
    s16x8 aq0 = *(const s16x8*)qp;
    s16x8 aq1 = *(const s16x8*)(qp + 32);

    f32x4 oacc[4];
    #pragma unroll
    for (int db = 0; db < 4; ++db) {
        oacc[db][0] = 0.f; oacc[db][1] = 0.f; oacc[db][2] = 0.f; oacc[db][3] = 0.f;
    }
    float mrun[4] = {-1e30f, -1e30f, -1e30f, -1e30f};
    float lrun[4] = {0.f, 0.f, 0.f, 0.f};

    const bf16* Kb = Kp + (size_t)(b * NK_) * ks + h * HD_;
    const bf16* Vb = Vp + (size_t)(b * NK_) * vs + h * HD_;

    for (int kt = 0; kt < NK_ / 64; ++kt) {
        __syncthreads();   // (A) previous tile's reads of Ks/Vt/Pl complete

        // --- stage K rows [w*16, w*16+16): 2 gload calls, pre-swizzled source.
        // lane covers row rowb + (l>>3), LDS unit (l&7); content must be
        // G(row, (l&7)^(row&7)); rowb%8==0 so row&7 = l>>3.
        {
            int rowb = w * 16;
            int srcu = ((l & 7) ^ (l >> 3)) * 8;
            gload_lds16(Kb + (size_t)(kt * 64 + rowb     + (l >> 3)) * ks + srcu, Ks + rowb * 64);
            gload_lds16(Kb + (size_t)(kt * 64 + rowb + 8 + (l >> 3)) * ks + srcu, Ks + (rowb + 8) * 64);
        }
        // --- stage Vt (transpose): 512 chunks of 8 bf16, 2 per thread
        #pragma unroll
        for (int i = 0; i < 2; ++i) {
            int f = tid + i * 256;                // 0..511
            int key = f >> 3, du = f & 7;
            u16x8 v = *(const u16x8*)(Vb + (size_t)(kt * 64 + key) * vs + du * 8);
            #pragma unroll
            for (int j = 0; j < 8; ++j) {
                int d = du * 8 + j;
                Vt[sw_u(d, key >> 3) + (key & 7)] = v[j];
            }
        }
        // --- masks (per lane: 4 q-rows, this tile's 64 keys)
        unsigned long long mb[4];
        if (pm) {
            #pragma unroll
            for (int r = 0; r < 4; ++r)
                mb[r] = pm[(size_t)(qn0 + (l >> 4) * 4 + r) * 16 + kt];
        } else {
            #pragma unroll
            for (int r = 0; r < 4; ++r) mb[r] = ~0ull;
        }
        __syncthreads();   // (B) staging visible (vmcnt+lgkm drained by barrier)

        // --- QK^T: S[16q][64k] in 4 col-groups of 16
        f32x4 s[4];
        #pragma unroll
        for (int kg = 0; kg < 4; ++kg) {
            s[kg][0] = 0.f; s[kg][1] = 0.f; s[kg][2] = 0.f; s[kg][3] = 0.f;
            int krow = kg * 16 + (l & 15);
            s16x8 b0 = *(const s16x8*)&Ks[sw_u(krow,     (l >> 4))];
            s16x8 b1 = *(const s16x8*)&Ks[sw_u(krow, 4 + (l >> 4))];
            s[kg] = __builtin_amdgcn_mfma_f32_16x16x32_bf16(aq0, b0, s[kg], 0, 0, 0);
            s[kg] = __builtin_amdgcn_mfma_f32_16x16x32_bf16(aq1, b1, s[kg], 0, 0, 0);
        }

        // --- online softmax per q-row r (lane holds rows (l>>4)*4+r, col l&15 per group)
        float corr[4];
        #pragma unroll
        for (int r = 0; r < 4; ++r) {
            float sv[4];
            #pragma unroll
            for (int kg = 0; kg < 4; ++kg) {
                bool ok = ((mb[r] >> (kg * 16 + (l & 15))) & 1ull) != 0;
                float t = s[kg][r] * SCALE_;
                sv[kg] = ok ? t : -1e30f;
            }
            float rm = fmaxf(fmaxf(sv[0], sv[1]), fmaxf(sv[2], sv[3]));
            #pragma unroll
            for (int msk = 1; msk < 16; msk <<= 1)
                rm = fmaxf(rm, __shfl_xor(rm, msk, 16));
            float mn = fmaxf(mrun[r], rm);
            corr[r] = __expf(mrun[r] - mn);
            int q = (l >> 4) * 4 + r;
            float rs = 0.f;
            #pragma unroll
            for (int kg = 0; kg < 4; ++kg) {
                bool ok = ((mb[r] >> (kg * 16 + (l & 15))) & 1ull) != 0;
                float p = ok ? __expf(sv[kg] - mn) : 0.0f;
                rs += p;
                bf16 pb = __float2bfloat16(p);
                int col = kg * 16 + (l & 15);
                Pl[w][sw_u(q, col >> 3) + (col & 7)] = *(unsigned short*)&pb;
            }
            #pragma unroll
            for (int msk = 1; msk < 16; msk <<= 1)
                rs += __shfl_xor(rs, msk, 16);
            lrun[r] = lrun[r] * corr[r] + rs;
            mrun[r] = mn;
        }
        __syncthreads();   // (C) P writes visible (lgkm drained)

        // --- rescale O by corr, then PV accumulate
        #pragma unroll
        for (int db = 0; db < 4; ++db)
            #pragma unroll
            for (int r = 0; r < 4; ++r)
                oacc[db][r] *= corr[r];

        #pragma unroll
        for (int half = 0; half < 2; ++half) {
            s16x8 pf = *(const s16x8*)&Pl[w][sw_u(l & 15, half * 4 + (l >> 4))];
            #pragma unroll
            for (int db = 0; db < 4; ++db) {
                s16x8 vf = *(const s16x8*)&Vt[sw_u(db * 16 + (l & 15), half * 4 + (l >> 4))];
                oacc[db] = __builtin_amdgcn_mfma_f32_16x16x32_bf16(pf, vf, oacc[db], 0, 0, 0);
            }
        }
    }

    // --- epilogue: O[q][d] = oacc / l
    #pragma unroll
    for (int r = 0; r < 4; ++r) {
        float inv = 1.0f / lrun[r];
        size_t row = (size_t)(b * NQ_ + qn0 + (l >> 4) * 4 + r) * C_ + h * HD_;
        #pragma unroll
        for (int db = 0; db < 4; ++db)
            O[row + db * 16 + (l & 15)] = __float2bfloat16(oacc[db][r] * inv);
    }
}

// ---------------------------------------------------------------- launch
extern "C" void kernel_launch(void* const* d_in, const int* in_sizes, int n_in,
                              void* d_out, int out_size, void* d_ws, size_t ws_size,
                              hipStream_t stream)
{
    const float* x           = (const float*)d_in[0];
    const float* y           = (const float*)d_in[1];
    const unsigned char* mask = (const unsigned char*)d_in[4];
    const float* qkv_w       = (const float*)d_in[5];
    const float* attn_proj_w = (const float*)d_in[6];
    const float* attn_proj_b = (const float*)d_in[7];
    const float* q_w         = (const float*)d_in[8];
    const float* k_w         = (const float*)d_in[9];
    const float* v_w         = (const float*)d_in[10];
    const float* ca_proj_w   = (const float*)d_in[11];
    const float* ca_proj_b   = (const float*)d_in[12];
    const float* fc1_w       = (const float*)d_in[13];
    const float* fc1_b       = (const float*)d_in[14];
    const float* fc2_w       = (const float*)d_in[15];
    const float* fc2_b       = (const float*)d_in[16];
    const float* ln1_g = (const float*)d_in[17], *ln1_b = (const float*)d_in[18];
    const float* ln2_g = (const float*)d_in[19], *ln2_b = (const float*)d_in[20];
    const float* ln3_g = (const float*)d_in[21], *ln3_b = (const float*)d_in[22];
    const float* lny_g = (const float*)d_in[23], *lny_b = (const float*)d_in[24];

    float* xo = (float*)d_out;
    float* ws = (float*)d_ws;
    bf16*  qkvBuf = (bf16*)ws;                        // bf16 8192x2304 (self qkv / cross q,k,v)
    bf16*  hBuf   = (bf16*)ws;                        // bf16 8192x3072 (fc1 out; disjoint lifetime)
    bf16*  lnBuf  = (bf16*)(ws + 18874368);           // bf16 8192x768
    bf16*  oBuf   = (bf16*)(ws + 22020096);           // bf16 8192x768
    bf16*  yBuf   = (bf16*)(ws + 25165824);           // bf16 8192x768
    bf16*  wts    = (bf16*)(ws + 28311552);           // 9,437,184 bf16
    unsigned long long* pm = (unsigned long long*)(ws + 33030144);  // 16384 u64
    int* mflag = (int*)(ws + 33030144 + 32768);

    bf16* qkv_w16  = wts;
    bf16* attn_w16 = wts + 1769472;
    bf16* q_w16    = wts + 2359296;
    bf16* k_w16    = wts + 2949120;
    bf16* v_w16    = wts + 3538944;
    bf16* ca_w16   = wts + 4128768;
    bf16* fc1_w16  = wts + 4718592;
    bf16* fc2_w16  = wts + 7077888;

    bf16* q_c = qkvBuf;                 // cross q (bf16, 8192x768 each)
    bf16* k_c = qkvBuf + 6291456;
    bf16* v_c = qkvBuf + 12582912;

    cast_bf16_k<<<1769472/1024, 256, 0, stream>>>(qkv_w,       qkv_w16, 1769472);
    cast_bf16_k<<< 589824/1024, 256, 0, stream>>>(attn_proj_w, attn_w16, 589824);
    cast_bf16_k<<< 589824/1024, 256, 0, stream>>>(q_w,         q_w16,   589824);
    cast_bf16_k<<< 589824/1024, 256, 0, stream>>>(k_w,         k_w16,   589824);
    cast_bf16_k<<< 589824/1024, 256, 0, stream>>>(v_w,         v_w16,   589824);
    cast_bf16_k<<< 589824/1024, 256, 0, stream>>>(ca_proj_w,   ca_w16,  589824);
    cast_bf16_k<<<2359296/1024, 256, 0, stream>>>(fc1_w,       fc1_w16, 2359296);
    cast_bf16_k<<<2359296/1024, 256, 0, stream>>>(fc2_w,       fc2_w16, 2359296);

    detect_mask_k<<<1, 64, 0, stream>>>(mask, mflag);
    pack_mask_k<<<64, 256, 0, stream>>>(mask, mflag, pm);

    // 1. h1 = ln1(x) -> bf16
    ln_k<<<M_, 256, 0, stream>>>(x, ln1_g, ln1_b, lnBuf);
    // 2. qkv = h1 @ qkv_w^T -> bf16
    gemm_mfma<0,1><<<dim3(2304/128, M_/128), 256, 0, stream>>>(lnBuf, qkv_w16, nullptr, nullptr, qkvBuf, 2304, 768);
    // 3. self MFMA flash attention -> oBuf bf16
    flash_mfma_k<<<dim3(NQ_/64, H_, B_), 256, 0, stream>>>(qkvBuf, 2304, qkvBuf + 768, 2304, qkvBuf + 1536, 2304, oBuf, nullptr);
    // 4. x1 = x + o @ attn_proj_w^T + b -> xo f32
    gemm_mfma<0,0><<<dim3(768/128, M_/128), 256, 0, stream>>>(oBuf, attn_w16, attn_proj_b, x, xo, 768, 768);
    // 5. y_ = lny(y) -> bf16
    ln_k<<<M_, 256, 0, stream>>>(y, lny_g, lny_b, yBuf);
    // 6. h2 = ln2(x1) -> bf16
    ln_k<<<M_, 256, 0, stream>>>(xo, ln2_g, ln2_b, lnBuf);
    // 7-9. cross q,k,v -> bf16
    gemm_mfma<0,1><<<dim3(768/128, M_/128), 256, 0, stream>>>(lnBuf, q_w16, nullptr, nullptr, q_c, 768, 768);
    gemm_mfma<0,1><<<dim3(768/128, M_/128), 256, 0, stream>>>(yBuf,  k_w16, nullptr, nullptr, k_c, 768, 768);
    gemm_mfma<0,1><<<dim3(768/128, M_/128), 256, 0, stream>>>(yBuf,  v_w16, nullptr, nullptr, v_c, 768, 768);
    // 10. cross MFMA flash attention (masked) -> oBuf bf16
    flash_mfma_k<<<dim3(NQ_/64, H_, B_), 256, 0, stream>>>(q_c, 768, k_c, 768, v_c, 768, oBuf, pm);
    // 11. x2 = x1 + o @ ca_proj_w^T + b (in-place on xo)
    gemm_mfma<0,0><<<dim3(768/128, M_/128), 256, 0, stream>>>(oBuf, ca_w16, ca_proj_b, xo, xo, 768, 768);
    // 12. h3 = ln3(x2) -> bf16
    ln_k<<<M_, 256, 0, stream>>>(xo, ln3_g, ln3_b, lnBuf);
    // 13. h = gelu(h3 @ fc1_w^T + b) -> hBuf bf16
    gemm_mfma<1,1><<<dim3(3072/128, M_/128), 256, 0, stream>>>(lnBuf, fc1_w16, fc1_b, nullptr, hBuf, 3072, 768);
    // 14. x3 = x2 + h @ fc2_w^T + b (in-place on xo)
    gemm_mfma<0,0><<<dim3(768/128, M_/128), 256, 0, stream>>>(hBuf, fc2_w16, fc2_b, xo, xo, 768, 3072);
    // 15. y passthrough
    hipMemcpyAsync(xo + 6291456, y, (size_t)6291456 * 4, hipMemcpyDeviceToDevice, stream);
}